// Round 11
// baseline (377.093 us; speedup 1.0000x reference)
//
#include <hip/hip_runtime.h>

#define DIMV 1024
#define NHV  16
#define HDV  64
#define BV   8
#define LQV  512
#define LKV  1024
#define PSTR 1032   // sP row stride in bf16: 2064B/row -> 2-way banks max (free)

typedef __bf16 bfrag  __attribute__((ext_vector_type(8)));
typedef float  f32x4  __attribute__((ext_vector_type(4)));
typedef unsigned short u16;
typedef unsigned int   u32;
typedef unsigned long long u64;
typedef u16 u16x8 __attribute__((ext_vector_type(8)));

typedef const __attribute__((address_space(1))) u32 gu32;
typedef __attribute__((address_space(3))) u32 lu32;

__device__ __forceinline__ u16 f2bf(float f) {
    u32 x = __builtin_bit_cast(u32, f);
    x = x + 0x7FFFu + ((x >> 16) & 1u);   // RNE
    return (u16)(x >> 16);
}

__device__ __forceinline__ float b2f(u16 v) {
    u32 x = ((u32)v) << 16;
    return __builtin_bit_cast(float, x);
}

// async global->LDS, 16B per lane; LDS dest must be wave-uniform base (+lane*16 implicit)
__device__ __forceinline__ void g2l16(const u16* g, const u16* l) {
    __builtin_amdgcn_global_load_lds(
        reinterpret_cast<gu32*>(reinterpret_cast<u64>(g)),
        reinterpret_cast<lu32*>((u32)reinterpret_cast<u64>(l)),
        16, 0, 0);
}

// All four fp32->bf16 casts in ONE dispatch (ranges exact multiples, no bounds checks)
__global__ __launch_bounds__(256)
void cast_all(const float* __restrict__ vis,  const float* __restrict__ wqkv,
              const float* __restrict__ outw, const float* __restrict__ text,
              u16* __restrict__ vis_bf, u16* __restrict__ wqkv_bf,
              u16* __restrict__ outw_bf, u16* __restrict__ text_bf)
{
    const int bx = blockIdx.x;
    const float* src; u16* dst; int i;
    if (bx < 8192)       { src = vis;  dst = vis_bf;  i = bx * 256 + threadIdx.x; }
    else if (bx < 11264) { src = wqkv; dst = wqkv_bf; i = (bx - 8192) * 256 + threadIdx.x; }
    else if (bx < 12288) { src = outw; dst = outw_bf; i = (bx - 11264) * 256 + threadIdx.x; }
    else                 { src = text; dst = text_bf; i = (bx - 12288) * 256 + threadIdx.x; }
    const float4 v = reinterpret_cast<const float4*>(src)[i];
    ushort4 o;
    o.x = f2bf(v.x); o.y = f2bf(v.y); o.z = f2bf(v.z); o.w = f2bf(v.w);
    reinterpret_cast<ushort4*>(dst)[i] = o;
}

// Q+K+V projections in ONE dispatch: grid.x = 32(Q) + 64(K) + 64(V^T) row-tiles,
// grid.y = 8 col-tiles. m97-style body; per-block uniform operand select.
__global__ __launch_bounds__(256)
void qkv_gemm(const u16* __restrict__ text_bf, const u16* __restrict__ vis_bf,
              const u16* __restrict__ wqkv_bf, const float* __restrict__ bqkv,
              u16* __restrict__ qb, u16* __restrict__ kb, u16* __restrict__ vTb)
{
    __shared__ __align__(16) u16 sA[128 * 64];
    __shared__ __align__(16) u16 sB[128 * 64];

    const int bx = blockIdx.x;
    const u16* A; const u16* W; const float* bias; u16* C; int mb, vmode;
    if (bx < 32)      { A = text_bf; W = wqkv_bf;               bias = bqkv;        C = qb;  mb = bx * 128;        vmode = 0; }
    else if (bx < 96) { A = vis_bf;  W = wqkv_bf + 1024 * 1024; bias = bqkv + 1024; C = kb;  mb = (bx - 32) * 128; vmode = 0; }
    else              { A = vis_bf;  W = wqkv_bf + 2097152;     bias = bqkv + 2048; C = vTb; mb = (bx - 96) * 128; vmode = 1; }

    const int t    = threadIdx.x;
    const int lane = t & 63;
    const int w    = t >> 6;
    const int quad = lane >> 4;
    const int r    = lane & 15;
    const int wr   = (w >> 1) * 64;
    const int wc   = (w & 1) * 64;
    const int nb   = blockIdx.y * 128;

    const int srow  = lane >> 3;
    const int skoff = (lane & 7) * 8;

    f32x4 acc[4][4] = {};

    const u16* Abase = A + (size_t)mb * 1024 + skoff;
    const u16* Wbase = W + (size_t)nb * 1024 + skoff;

    for (int k0 = 0; k0 < 1024; k0 += 64) {
#pragma unroll
        for (int it = 0; it < 4; ++it) {
            const int c = w * 4 + it;
            const int row = c * 8 + srow;
            g2l16(Abase + (size_t)row * 1024 + k0, sA + c * 512);
            g2l16(Wbase + (size_t)row * 1024 + k0, sB + c * 512);
        }
        __syncthreads();
#pragma unroll
        for (int kk = 0; kk < 2; ++kk) {
            bfrag af[4], bg[4];
#pragma unroll
            for (int i = 0; i < 4; ++i)
                af[i] = *reinterpret_cast<const bfrag*>(sA + (wr + i * 16 + r) * 64 + kk * 32 + quad * 8);
#pragma unroll
            for (int j = 0; j < 4; ++j)
                bg[j] = *reinterpret_cast<const bfrag*>(sB + (wc + j * 16 + r) * 64 + kk * 32 + quad * 8);
#pragma unroll
            for (int i = 0; i < 4; ++i)
#pragma unroll
                for (int j = 0; j < 4; ++j)
                    acc[i][j] = __builtin_amdgcn_mfma_f32_16x16x32_bf16(af[i], bg[j], acc[i][j], 0, 0, 0);
        }
        __syncthreads();
    }

#pragma unroll
    for (int i = 0; i < 4; i++)
#pragma unroll
    for (int j = 0; j < 4; j++) {
        const int colg = nb + wc + j * 16 + r;
        const float bv = bias[colg];
#pragma unroll
        for (int reg = 0; reg < 4; reg++) {
            const int rowg = mb + wr + i * 16 + quad * 4 + reg;
            const float v = acc[i][j][reg] + bv;
            if (vmode == 0) {
                C[(size_t)rowg * 1024 + colg] = f2bf(v);
            } else {
                C[((size_t)((rowg >> 10) << 10) + colg) * 1024 + (rowg & 1023)] = f2bf(v);
            }
        }
    }
}

// Stage-5 GEMM: attended = ctx @ out_w^T + out_b + text (fp32 out with residual)
__global__ __launch_bounds__(256)
void gemm_out(const u16* __restrict__ A, const u16* __restrict__ W,
              const float* __restrict__ bias, float* __restrict__ Cout,
              const float* __restrict__ resid)
{
    __shared__ __align__(16) u16 sA[128 * 64];
    __shared__ __align__(16) u16 sB[128 * 64];

    const int t    = threadIdx.x;
    const int lane = t & 63;
    const int w    = t >> 6;
    const int quad = lane >> 4;
    const int r    = lane & 15;
    const int wr   = (w >> 1) * 64;
    const int wc   = (w & 1) * 64;
    const int mb   = blockIdx.x * 128;
    const int nb   = blockIdx.y * 128;

    const int srow  = lane >> 3;
    const int skoff = (lane & 7) * 8;

    f32x4 acc[4][4] = {};

    const u16* Abase = A + (size_t)mb * 1024 + skoff;
    const u16* Wbase = W + (size_t)nb * 1024 + skoff;

    for (int k0 = 0; k0 < 1024; k0 += 64) {
#pragma unroll
        for (int it = 0; it < 4; ++it) {
            const int c = w * 4 + it;
            const int row = c * 8 + srow;
            g2l16(Abase + (size_t)row * 1024 + k0, sA + c * 512);
            g2l16(Wbase + (size_t)row * 1024 + k0, sB + c * 512);
        }
        __syncthreads();
#pragma unroll
        for (int kk = 0; kk < 2; ++kk) {
            bfrag af[4], bg[4];
#pragma unroll
            for (int i = 0; i < 4; ++i)
                af[i] = *reinterpret_cast<const bfrag*>(sA + (wr + i * 16 + r) * 64 + kk * 32 + quad * 8);
#pragma unroll
            for (int j = 0; j < 4; ++j)
                bg[j] = *reinterpret_cast<const bfrag*>(sB + (wc + j * 16 + r) * 64 + kk * 32 + quad * 8);
#pragma unroll
            for (int i = 0; i < 4; ++i)
#pragma unroll
                for (int j = 0; j < 4; ++j)
                    acc[i][j] = __builtin_amdgcn_mfma_f32_16x16x32_bf16(af[i], bg[j], acc[i][j], 0, 0, 0);
        }
        __syncthreads();
    }

#pragma unroll
    for (int i = 0; i < 4; i++)
#pragma unroll
    for (int j = 0; j < 4; j++) {
        const int colg = nb + wc + j * 16 + r;
        const float bv = bias[colg];
#pragma unroll
        for (int reg = 0; reg < 4; reg++) {
            const int rowg = mb + wr + i * 16 + quad * 4 + reg;
            const float v = acc[i][j][reg] + bv;
            Cout[(size_t)rowg * 1024 + colg] = v + resid[(size_t)rowg * 1024 + colg];
        }
    }
}

// Attention v12 = v11 with the register-liveness wall removed:
//  - chunked QK (4x4): exp+sP-write per chunk -> s liveness 64->16 regs and
//    scores never live across the barrier.
//  - wacc re-sourced from LDS: post-barrier, each thread owns a disjoint
//    1-row x 32-col attnw slice and accumulates from BOTH groups' raw-exp sP
//    (bf16) with both factors. wacc 64->32 regs; epilogue combine + 2 barriers
//    GONE (plain final store).
//  - s_setprio(1) around PV MFMA cluster (T5: +4-7% attn, m191).
//  - launch_bounds(512,2) kept as the <=128-VGPR guard (r6/r7): freed regs go
//    to deeper K-load pipelining inside the cap, not past it.
// Grid (8 b, 32 q): b-major keeps XCD L2 affinity (FETCH ~20MB, r5/r7/r9).
__global__ __launch_bounds__(512, 2)
void attn_kernel(const u16* __restrict__ q, const u16* __restrict__ k,
                 const u16* __restrict__ vT, u16* __restrict__ ctx,
                 float* __restrict__ attnw)
{
    __shared__ __align__(16) u16 sP[2][2][16 * PSTR];   // [group][parity], 132096 B
    __shared__ float reds[2][2][64];                     // [group][parity]

    const int t    = threadIdx.x;     // 0..511
    const int g    = t >> 8;          // head-group 0/1 (8 heads each)
    const int tg   = t & 255;         // thread within group
    const int lane = tg & 63;
    const int w    = tg >> 6;         // wave 0..3 within group
    const int quad = lane >> 4;       // 0..3
    const int r    = lane & 15;
    const int b    = blockIdx.x;      // batch -> XCD affinity (grid.x == 8)
    const int q0   = blockIdx.y * 16;

    const int row16 = quad * 4;
    const float scale = 0.125f;       // 1/sqrt(64); folded into exp arg

    // attnw ownership: thread -> q-row (t&15), 32 k-cols at (t>>4)*32.
    // (row = t&15 keeps the per-head sP reads ~4-way banked, not 16-way.)
    const int arow = t & 15;
    const int ac0  = (t >> 4) * 32;

    float wacc[32] = {};

    for (int hh = 0; hh < 8; ++hh) {
        const int h = g * 8 + hh;
        const int p = hh & 1;         // sP/reds parity
        const int dbase = h * HDV + quad * 8;

        const u16* qp = q + (size_t)(b * LQV + q0 + r) * DIMV + dbase;
        const bfrag qa0 = *reinterpret_cast<const bfrag*>(qp);
        const bfrag qa1 = *reinterpret_cast<const bfrag*>(qp + 32);

        // ---- chunked QK: 4 chunks x 4 iters; s4 dies at sP-write ----
        float sw[4] = {0.f, 0.f, 0.f, 0.f};
#pragma unroll
        for (int ch = 0; ch < 4; ++ch) {
            f32x4 s4[4];
#pragma unroll
            for (int u = 0; u < 4; ++u) {
                const int i = ch * 4 + u;
                const u16* kp = k + (size_t)(b * LKV + w * 256 + i * 16 + r) * DIMV + dbase;
                const bfrag kb0 = *reinterpret_cast<const bfrag*>(kp);
                const bfrag kb1 = *reinterpret_cast<const bfrag*>(kp + 32);
                f32x4 a = {};
                a     = __builtin_amdgcn_mfma_f32_16x16x32_bf16(qa0, kb0, a, 0, 0, 0);
                s4[u] = __builtin_amdgcn_mfma_f32_16x16x32_bf16(qa1, kb1, a, 0, 0, 0);
            }
#pragma unroll
            for (int u = 0; u < 4; ++u) {
                const int i = ch * 4 + u;
#pragma unroll
                for (int reg = 0; reg < 4; ++reg) {
                    const float e = __expf(s4[u][reg] * scale);
                    sw[reg] += e;
                    sP[g][p][(row16 + reg) * PSTR + w * 256 + i * 16 + r] = f2bf(e);
                }
            }
        }

        // ---- wave-local row sums -> reds ----
#pragma unroll
        for (int reg = 0; reg < 4; ++reg)
#pragma unroll
            for (int off = 1; off < 16; off <<= 1)
                sw[reg] += __shfl_xor(sw[reg], off);
        if (r == 0) {
#pragma unroll
            for (int reg = 0; reg < 4; ++reg)
                reds[g][p][w * 16 + row16 + reg] = sw[reg];
        }

        __syncthreads();   // single barrier: reds+P(h) visible; fences parity reuse

        // ---- PV factor (quad-row indexed, this group's head) ----
        float factor[4];
#pragma unroll
        for (int reg = 0; reg < 4; ++reg) {
            const int rr = row16 + reg;
            factor[reg] = 1.0f / (reds[g][p][rr]      + reds[g][p][16 + rr] +
                                  reds[g][p][32 + rr] + reds[g][p][48 + rr]);
        }

        // ---- attnw incremental: thread's slice from BOTH groups' raw sP ----
        {
            const float f0 = 1.0f / (reds[0][p][arow]      + reds[0][p][16 + arow] +
                                     reds[0][p][32 + arow] + reds[0][p][48 + arow]);
            const float f1 = 1.0f / (reds[1][p][arow]      + reds[1][p][16 + arow] +
                                     reds[1][p][32 + arow] + reds[1][p][48 + arow]);
#pragma unroll
            for (int m = 0; m < 4; ++m) {
                const u16x8 p0 = *reinterpret_cast<const u16x8*>(&sP[0][p][arow * PSTR + ac0 + m * 8]);
                const u16x8 p1 = *reinterpret_cast<const u16x8*>(&sP[1][p][arow * PSTR + ac0 + m * 8]);
#pragma unroll
                for (int e = 0; e < 8; ++e)
                    wacc[m * 8 + e] += b2f(p0[e]) * f0 + b2f(p1[e]) * f1;
            }
        }

        // ---- PV on raw P; normalize ctx after MFMA ----
        {
            const int n0 = w * 16;
            f32x4 c0 = {}, c1 = {}, c2 = {}, c3 = {};
            const u16* vb = vT + (size_t)(b * DIMV + h * HDV + n0 + r) * LKV;
            const u16* sPb = &sP[g][p][r * PSTR + quad * 8];
            __builtin_amdgcn_s_setprio(1);
#pragma unroll
            for (int kk = 0; kk < LKV; kk += 128) {
                const bfrag a0 = *reinterpret_cast<const bfrag*>(sPb + kk);
                const bfrag a1 = *reinterpret_cast<const bfrag*>(sPb + kk + 32);
                const bfrag a2 = *reinterpret_cast<const bfrag*>(sPb + kk + 64);
                const bfrag a3 = *reinterpret_cast<const bfrag*>(sPb + kk + 96);
                const bfrag b0 = *reinterpret_cast<const bfrag*>(vb + kk      + quad * 8);
                const bfrag b1 = *reinterpret_cast<const bfrag*>(vb + kk + 32 + quad * 8);
                const bfrag b2 = *reinterpret_cast<const bfrag*>(vb + kk + 64 + quad * 8);
                const bfrag b3 = *reinterpret_cast<const bfrag*>(vb + kk + 96 + quad * 8);
                c0 = __builtin_amdgcn_mfma_f32_16x16x32_bf16(a0, b0, c0, 0, 0, 0);
                c1 = __builtin_amdgcn_mfma_f32_16x16x32_bf16(a1, b1, c1, 0, 0, 0);
                c2 = __builtin_amdgcn_mfma_f32_16x16x32_bf16(a2, b2, c2, 0, 0, 0);
                c3 = __builtin_amdgcn_mfma_f32_16x16x32_bf16(a3, b3, c3, 0, 0, 0);
            }
            __builtin_amdgcn_s_setprio(0);
            const f32x4 c = (c0 + c1) + (c2 + c3);
#pragma unroll
            for (int reg = 0; reg < 4; ++reg)
                ctx[(size_t)(b * LQV + q0 + row16 + reg) * DIMV + h * HDV + n0 + r] =
                    f2bf(c[reg] * factor[reg]);
        }
        // NO trailing barrier: next head uses the other parity; parity-p rewrite
        // (h+2) happens after barrier(h+1), which this wave reaches only after
        // its PV(h)/wacc(h) LDS reads retire (barrier drains lgkmcnt).
    }

    // ---- attnw final store: full ownership, plain coalesced-ish stores ----
    {
        const float inv16 = 1.0f / 16.0f;
        float* ap = attnw + (size_t)(b * LQV + q0 + arow) * LKV + ac0;
#pragma unroll
        for (int j = 0; j < 32; j += 4) {
            float4 o;
            o.x = wacc[j]     * inv16;
            o.y = wacc[j + 1] * inv16;
            o.z = wacc[j + 2] * inv16;
            o.w = wacc[j + 3] * inv16;
            *reinterpret_cast<float4*>(ap + j) = o;
        }
    }
}

// LayerNorm per row of 1024; x fp32 (attended+residual), g/b fp32, out fp32
__global__ __launch_bounds__(256)
void ln_kernel(const float* __restrict__ x, const float* __restrict__ g,
               const float* __restrict__ bta, float* __restrict__ out)
{
    __shared__ float red[8];
    const int row = blockIdx.x;
    const int t = threadIdx.x;
    const int w = t >> 6;
    const float4 xv = reinterpret_cast<const float4*>(x + (size_t)row * DIMV)[t];

    float s = xv.x + xv.y + xv.z + xv.w;
#pragma unroll
    for (int off = 32; off; off >>= 1) s += __shfl_down(s, off);
    if ((t & 63) == 0) red[w] = s;
    __syncthreads();
    const float mu = (red[0] + red[1] + red[2] + red[3]) * (1.0f / 1024.0f);

    const float d0 = xv.x - mu, d1 = xv.y - mu, d2 = xv.z - mu, d3 = xv.w - mu;
    float s2 = d0 * d0 + d1 * d1 + d2 * d2 + d3 * d3;
#pragma unroll
    for (int off = 32; off; off >>= 1) s2 += __shfl_down(s2, off);
    if ((t & 63) == 0) red[4 + w] = s2;
    __syncthreads();
    const float var = (red[4] + red[5] + red[6] + red[7]) * (1.0f / 1024.0f);
    const float inv = rsqrtf(var + 1e-5f);

    float4 o;
    const int c = t * 4;
    o.x = d0 * inv * g[c + 0] + bta[c + 0];
    o.y = d1 * inv * g[c + 1] + bta[c + 1];
    o.z = d2 * inv * g[c + 2] + bta[c + 2];
    o.w = d3 * inv * g[c + 3] + bta[c + 3];
    reinterpret_cast<float4*>(out + (size_t)row * DIMV)[t] = o;
}

extern "C" void kernel_launch(void* const* d_in, const int* in_sizes, int n_in,
                              void* d_out, int out_size, void* d_ws, size_t ws_size,
                              hipStream_t stream)
{
    const float* text = (const float*)d_in[0];   // (8,512,1024)
    const float* vis  = (const float*)d_in[1];   // (8,1024,1024)
    const float* wqkv = (const float*)d_in[2];   // (3072,1024)
    const float* bqkv = (const float*)d_in[3];   // (3072,)
    const float* outw = (const float*)d_in[4];   // (1024,1024)
    const float* outb = (const float*)d_in[5];   // (1024,)
    const float* lng  = (const float*)d_in[6];   // (1024,)
    const float* lnb  = (const float*)d_in[7];   // (1024,)

    // Workspace overlays (64 MiB). text_bf lives in d_out's out-region
    // (dead until ln_kernel rewrites it) so kb doesn't alias it.
    char* ws = (char*)d_ws;
    u16*   vis_bf  = (u16*)(ws);                          // 0-16M
    u16*   ctxb    = (u16*)(ws);                          // 0-8M   (attn w; gemm_out r)
    u16*   wqkv_bf = (u16*)(ws + (size_t)(16u << 20));    // 16-22M
    u16*   outw_bf = (u16*)(ws + (size_t)(22u << 20));    // 22-24M
    u16*   qb      = (u16*)(ws + (size_t)(24u << 20));    // 24-32M
    u16*   kb      = (u16*)(ws + (size_t)(32u << 20));    // 32-48M
    float* attb    = (float*)(ws + (size_t)(32u << 20));  // 32-48M (gemm_out w; ln r)
    u16*   vTb     = (u16*)(ws + (size_t)(48u << 20));    // 48-64M

    float* outp  = (float*)d_out;                 // fp32 outputs, concat (out, attn_weights)
    float* attnw = outp + (size_t)4096 * 1024;
    u16*   text_bf = (u16*)outp;                  // 8MB scratch in out-region

    const dim3 blk(256);
    // stage 0: all casts, one dispatch
    cast_all<<<dim3(16384), blk, 0, stream>>>(vis, wqkv, outw, text,
                                              vis_bf, wqkv_bf, outw_bf, text_bf);
    // stage 1: Q,K,V^T projections, one dispatch (1280 blocks)
    qkv_gemm<<<dim3(160, 8), blk, 0, stream>>>(text_bf, vis_bf, wqkv_bf, bqkv, qb, kb, vTb);
    // stage 2: attention; chunked QK, LDS-sourced attnw, setprio PV, no atomics
    attn_kernel<<<dim3(8, 32), dim3(512), 0, stream>>>(qb, kb, vTb, ctxb, attnw);
    // stage 3: attended = ctx @ out_w^T + out_b + text (fp32), over dead kb
    gemm_out<<<dim3(32, 8), blk, 0, stream>>>(ctxb, outw_bf, outb, attb, text);
    // stage 4: layernorm -> out (fp32)
    ln_kernel<<<dim3(4096), blk, 0, stream>>>(attb, lng, lnb, outp);
}

// Round 12
// 368.739 us; speedup vs baseline: 1.0227x; 1.0227x over previous
//
#include <hip/hip_runtime.h>

#define DIMV 1024
#define NHV  16
#define HDV  64
#define BV   8
#define LQV  512
#define LKV  1024
#define PSTR 1032   // sP row stride in bf16: 2064B/row -> 2-way banks max (free)

typedef __bf16 bfrag  __attribute__((ext_vector_type(8)));
typedef float  f32x4  __attribute__((ext_vector_type(4)));
typedef unsigned short u16;
typedef unsigned int   u32;
typedef unsigned long long u64;
typedef u16 u16x8 __attribute__((ext_vector_type(8)));

typedef const __attribute__((address_space(1))) u32 gu32;
typedef __attribute__((address_space(3))) u32 lu32;

__device__ __forceinline__ u16 f2bf(float f) {
    u32 x = __builtin_bit_cast(u32, f);
    x = x + 0x7FFFu + ((x >> 16) & 1u);   // RNE
    return (u16)(x >> 16);
}

__device__ __forceinline__ float b2f(u16 v) {
    u32 x = ((u32)v) << 16;
    return __builtin_bit_cast(float, x);
}

// async global->LDS, 16B per lane; LDS dest must be wave-uniform base (+lane*16 implicit)
__device__ __forceinline__ void g2l16(const u16* g, const u16* l) {
    __builtin_amdgcn_global_load_lds(
        reinterpret_cast<gu32*>(reinterpret_cast<u64>(g)),
        reinterpret_cast<lu32*>((u32)reinterpret_cast<u64>(l)),
        16, 0, 0);
}

// All four fp32->bf16 casts in ONE dispatch (ranges exact multiples, no bounds checks)
__global__ __launch_bounds__(256)
void cast_all(const float* __restrict__ vis,  const float* __restrict__ wqkv,
              const float* __restrict__ outw, const float* __restrict__ text,
              u16* __restrict__ vis_bf, u16* __restrict__ wqkv_bf,
              u16* __restrict__ outw_bf, u16* __restrict__ text_bf)
{
    const int bx = blockIdx.x;
    const float* src; u16* dst; int i;
    if (bx < 8192)       { src = vis;  dst = vis_bf;  i = bx * 256 + threadIdx.x; }
    else if (bx < 11264) { src = wqkv; dst = wqkv_bf; i = (bx - 8192) * 256 + threadIdx.x; }
    else if (bx < 12288) { src = outw; dst = outw_bf; i = (bx - 11264) * 256 + threadIdx.x; }
    else                 { src = text; dst = text_bf; i = (bx - 12288) * 256 + threadIdx.x; }
    const float4 v = reinterpret_cast<const float4*>(src)[i];
    ushort4 o;
    o.x = f2bf(v.x); o.y = f2bf(v.y); o.z = f2bf(v.z); o.w = f2bf(v.w);
    reinterpret_cast<ushort4*>(dst)[i] = o;
}

// Q+K+V projections in ONE dispatch: grid.x = 32(Q) + 64(K) + 64(V^T) row-tiles,
// grid.y = 8 col-tiles. m97-style body; per-block uniform operand select.
__global__ __launch_bounds__(256)
void qkv_gemm(const u16* __restrict__ text_bf, const u16* __restrict__ vis_bf,
              const u16* __restrict__ wqkv_bf, const float* __restrict__ bqkv,
              u16* __restrict__ qb, u16* __restrict__ kb, u16* __restrict__ vTb)
{
    __shared__ __align__(16) u16 sA[128 * 64];
    __shared__ __align__(16) u16 sB[128 * 64];

    const int bx = blockIdx.x;
    const u16* A; const u16* W; const float* bias; u16* C; int mb, vmode;
    if (bx < 32)      { A = text_bf; W = wqkv_bf;               bias = bqkv;        C = qb;  mb = bx * 128;        vmode = 0; }
    else if (bx < 96) { A = vis_bf;  W = wqkv_bf + 1024 * 1024; bias = bqkv + 1024; C = kb;  mb = (bx - 32) * 128; vmode = 0; }
    else              { A = vis_bf;  W = wqkv_bf + 2097152;     bias = bqkv + 2048; C = vTb; mb = (bx - 96) * 128; vmode = 1; }

    const int t    = threadIdx.x;
    const int lane = t & 63;
    const int w    = t >> 6;
    const int quad = lane >> 4;
    const int r    = lane & 15;
    const int wr   = (w >> 1) * 64;
    const int wc   = (w & 1) * 64;
    const int nb   = blockIdx.y * 128;

    const int srow  = lane >> 3;
    const int skoff = (lane & 7) * 8;

    f32x4 acc[4][4] = {};

    const u16* Abase = A + (size_t)mb * 1024 + skoff;
    const u16* Wbase = W + (size_t)nb * 1024 + skoff;

    for (int k0 = 0; k0 < 1024; k0 += 64) {
#pragma unroll
        for (int it = 0; it < 4; ++it) {
            const int c = w * 4 + it;
            const int row = c * 8 + srow;
            g2l16(Abase + (size_t)row * 1024 + k0, sA + c * 512);
            g2l16(Wbase + (size_t)row * 1024 + k0, sB + c * 512);
        }
        __syncthreads();
#pragma unroll
        for (int kk = 0; kk < 2; ++kk) {
            bfrag af[4], bg[4];
#pragma unroll
            for (int i = 0; i < 4; ++i)
                af[i] = *reinterpret_cast<const bfrag*>(sA + (wr + i * 16 + r) * 64 + kk * 32 + quad * 8);
#pragma unroll
            for (int j = 0; j < 4; ++j)
                bg[j] = *reinterpret_cast<const bfrag*>(sB + (wc + j * 16 + r) * 64 + kk * 32 + quad * 8);
#pragma unroll
            for (int i = 0; i < 4; ++i)
#pragma unroll
                for (int j = 0; j < 4; ++j)
                    acc[i][j] = __builtin_amdgcn_mfma_f32_16x16x32_bf16(af[i], bg[j], acc[i][j], 0, 0, 0);
        }
        __syncthreads();
    }

#pragma unroll
    for (int i = 0; i < 4; i++)
#pragma unroll
    for (int j = 0; j < 4; j++) {
        const int colg = nb + wc + j * 16 + r;
        const float bv = bias[colg];
#pragma unroll
        for (int reg = 0; reg < 4; reg++) {
            const int rowg = mb + wr + i * 16 + quad * 4 + reg;
            const float v = acc[i][j][reg] + bv;
            if (vmode == 0) {
                C[(size_t)rowg * 1024 + colg] = f2bf(v);
            } else {
                C[((size_t)((rowg >> 10) << 10) + colg) * 1024 + (rowg & 1023)] = f2bf(v);
            }
        }
    }
}

// Stage-3 GEMM, split-K: z-half computes K range [z*512, z*512+512) and stores
// RAW partial sums to attb + z*4M floats. 512 blocks (2/CU) vs 256 (1/CU).
// bias + residual + combine move to ln_kernel.
__global__ __launch_bounds__(256)
void gemm_out(const u16* __restrict__ A, const u16* __restrict__ W,
              float* __restrict__ attb)
{
    __shared__ __align__(16) u16 sA[128 * 64];
    __shared__ __align__(16) u16 sB[128 * 64];

    const int t    = threadIdx.x;
    const int lane = t & 63;
    const int w    = t >> 6;
    const int quad = lane >> 4;
    const int r    = lane & 15;
    const int wr   = (w >> 1) * 64;
    const int wc   = (w & 1) * 64;
    const int mb   = blockIdx.x * 128;
    const int nb   = blockIdx.y * 128;
    const int z    = blockIdx.z;
    float* Cout    = attb + (size_t)z * 4096 * 1024;

    const int srow  = lane >> 3;
    const int skoff = (lane & 7) * 8;

    f32x4 acc[4][4] = {};

    const u16* Abase = A + (size_t)mb * 1024 + skoff;
    const u16* Wbase = W + (size_t)nb * 1024 + skoff;

    for (int k0 = z * 512; k0 < z * 512 + 512; k0 += 64) {
#pragma unroll
        for (int it = 0; it < 4; ++it) {
            const int c = w * 4 + it;
            const int row = c * 8 + srow;
            g2l16(Abase + (size_t)row * 1024 + k0, sA + c * 512);
            g2l16(Wbase + (size_t)row * 1024 + k0, sB + c * 512);
        }
        __syncthreads();
#pragma unroll
        for (int kk = 0; kk < 2; ++kk) {
            bfrag af[4], bg[4];
#pragma unroll
            for (int i = 0; i < 4; ++i)
                af[i] = *reinterpret_cast<const bfrag*>(sA + (wr + i * 16 + r) * 64 + kk * 32 + quad * 8);
#pragma unroll
            for (int j = 0; j < 4; ++j)
                bg[j] = *reinterpret_cast<const bfrag*>(sB + (wc + j * 16 + r) * 64 + kk * 32 + quad * 8);
#pragma unroll
            for (int i = 0; i < 4; ++i)
#pragma unroll
                for (int j = 0; j < 4; ++j)
                    acc[i][j] = __builtin_amdgcn_mfma_f32_16x16x32_bf16(af[i], bg[j], acc[i][j], 0, 0, 0);
        }
        __syncthreads();
    }

#pragma unroll
    for (int i = 0; i < 4; i++)
#pragma unroll
    for (int j = 0; j < 4; j++) {
        const int colg = nb + wc + j * 16 + r;
#pragma unroll
        for (int reg = 0; reg < 4; reg++) {
            const int rowg = mb + wr + i * 16 + quad * 4 + reg;
            Cout[(size_t)rowg * 1024 + colg] = acc[i][j][reg];
        }
    }
}

// Attention v13 = v12 math with TLP doubled: ONE 1024-thread block per (b,q0)
// tile -> 16 waves/CU co-resident (vs v12's 8). Round-11 lesson: freeing VGPRs
// (116->92) changed nothing -> not register-MLP-bound; the compiler won't
// pipeline deeper, so latency must be hidden by MORE WAVES. 4 groups x 4 waves,
// each group 4 serial heads (vs 8): serial depth halves. Single sP buffer per
// group (no parity): 2 barriers/head x 4 heads = 8 barriers/block, same count
// as v12. LDS 133KB (same). At 92-128 VGPR the HW quantum allows 4 waves/SIMD
// (m69) -> the single block's 16 waves all fit. Grid (8 b, 32 q): b-major XCD
// L2 affinity retained (FETCH ~20MB).
__global__ __launch_bounds__(1024)
void attn_kernel(const u16* __restrict__ q, const u16* __restrict__ k,
                 const u16* __restrict__ vT, u16* __restrict__ ctx,
                 float* __restrict__ attnw)
{
    __shared__ __align__(16) u16 sP[4][16 * PSTR];   // 132096 B
    __shared__ float reds[4][64];

    const int t    = threadIdx.x;     // 0..1023
    const int g    = t >> 8;          // group 0..3 (4 heads each)
    const int tg   = t & 255;         // thread within group
    const int lane = tg & 63;
    const int w    = tg >> 6;         // wave 0..3 within group
    const int quad = lane >> 4;       // 0..3
    const int r    = lane & 15;
    const int b    = blockIdx.x;      // batch -> XCD affinity (grid.x == 8)
    const int q0   = blockIdx.y * 16;

    const int row16 = quad * 4;
    const float scale = 0.125f;       // 1/sqrt(64); folded into exp arg

    // attnw ownership: thread -> q-row (t&15), 16 k-cols at (t>>4)*16.
    const int arow = t & 15;
    const int ac0  = (t >> 4) * 16;

    float wacc[16] = {};

    for (int hh = 0; hh < 4; ++hh) {
        const int h = g * 4 + hh;
        const int dbase = h * HDV + quad * 8;

        const u16* qp = q + (size_t)(b * LQV + q0 + r) * DIMV + dbase;
        const bfrag qa0 = *reinterpret_cast<const bfrag*>(qp);
        const bfrag qa1 = *reinterpret_cast<const bfrag*>(qp + 32);

        // ---- chunked QK: 4 chunks x 4 iters; s4 dies at sP-write ----
        float sw[4] = {0.f, 0.f, 0.f, 0.f};
#pragma unroll
        for (int ch = 0; ch < 4; ++ch) {
            f32x4 s4[4];
#pragma unroll
            for (int u = 0; u < 4; ++u) {
                const int i = ch * 4 + u;
                const u16* kp = k + (size_t)(b * LKV + w * 256 + i * 16 + r) * DIMV + dbase;
                const bfrag kb0 = *reinterpret_cast<const bfrag*>(kp);
                const bfrag kb1 = *reinterpret_cast<const bfrag*>(kp + 32);
                f32x4 a = {};
                a     = __builtin_amdgcn_mfma_f32_16x16x32_bf16(qa0, kb0, a, 0, 0, 0);
                s4[u] = __builtin_amdgcn_mfma_f32_16x16x32_bf16(qa1, kb1, a, 0, 0, 0);
            }
#pragma unroll
            for (int u = 0; u < 4; ++u) {
                const int i = ch * 4 + u;
#pragma unroll
                for (int reg = 0; reg < 4; ++reg) {
                    const float e = __expf(s4[u][reg] * scale);
                    sw[reg] += e;
                    sP[g][(row16 + reg) * PSTR + w * 256 + i * 16 + r] = f2bf(e);
                }
            }
        }

        // ---- wave-local row sums -> reds ----
#pragma unroll
        for (int reg = 0; reg < 4; ++reg)
#pragma unroll
            for (int off = 1; off < 16; off <<= 1)
                sw[reg] += __shfl_xor(sw[reg], off);
        if (r == 0) {
#pragma unroll
            for (int reg = 0; reg < 4; ++reg)
                reds[g][w * 16 + row16 + reg] = sw[reg];
        }

        __syncthreads();   // bar A: all groups' reds+P(h) visible

        // ---- PV factor (quad-row indexed, this group's head) ----
        float factor[4];
#pragma unroll
        for (int reg = 0; reg < 4; ++reg) {
            const int rr = row16 + reg;
            factor[reg] = 1.0f / (reds[g][rr]      + reds[g][16 + rr] +
                                  reds[g][32 + rr] + reds[g][48 + rr]);
        }

        // ---- attnw incremental: thread's 16-col slice from ALL 4 groups ----
        {
            float fg[4];
#pragma unroll
            for (int gg = 0; gg < 4; ++gg)
                fg[gg] = 1.0f / (reds[gg][arow]      + reds[gg][16 + arow] +
                                 reds[gg][32 + arow] + reds[gg][48 + arow]);
#pragma unroll
            for (int gg = 0; gg < 4; ++gg) {
                const u16x8 p0 = *reinterpret_cast<const u16x8*>(&sP[gg][arow * PSTR + ac0]);
                const u16x8 p1 = *reinterpret_cast<const u16x8*>(&sP[gg][arow * PSTR + ac0 + 8]);
#pragma unroll
                for (int e = 0; e < 8; ++e) {
                    wacc[e]     += b2f(p0[e]) * fg[gg];
                    wacc[8 + e] += b2f(p1[e]) * fg[gg];
                }
            }
        }

        // ---- PV on raw P; normalize ctx after MFMA ----
        {
            const int n0 = w * 16;
            f32x4 c0 = {}, c1 = {}, c2 = {}, c3 = {};
            const u16* vb = vT + (size_t)(b * DIMV + h * HDV + n0 + r) * LKV;
            const u16* sPb = &sP[g][r * PSTR + quad * 8];
            __builtin_amdgcn_s_setprio(1);
#pragma unroll
            for (int kk = 0; kk < LKV; kk += 128) {
                const bfrag a0 = *reinterpret_cast<const bfrag*>(sPb + kk);
                const bfrag a1 = *reinterpret_cast<const bfrag*>(sPb + kk + 32);
                const bfrag a2 = *reinterpret_cast<const bfrag*>(sPb + kk + 64);
                const bfrag a3 = *reinterpret_cast<const bfrag*>(sPb + kk + 96);
                const bfrag b0 = *reinterpret_cast<const bfrag*>(vb + kk      + quad * 8);
                const bfrag b1 = *reinterpret_cast<const bfrag*>(vb + kk + 32 + quad * 8);
                const bfrag b2 = *reinterpret_cast<const bfrag*>(vb + kk + 64 + quad * 8);
                const bfrag b3 = *reinterpret_cast<const bfrag*>(vb + kk + 96 + quad * 8);
                c0 = __builtin_amdgcn_mfma_f32_16x16x32_bf16(a0, b0, c0, 0, 0, 0);
                c1 = __builtin_amdgcn_mfma_f32_16x16x32_bf16(a1, b1, c1, 0, 0, 0);
                c2 = __builtin_amdgcn_mfma_f32_16x16x32_bf16(a2, b2, c2, 0, 0, 0);
                c3 = __builtin_amdgcn_mfma_f32_16x16x32_bf16(a3, b3, c3, 0, 0, 0);
            }
            __builtin_amdgcn_s_setprio(0);
            const f32x4 c = (c0 + c1) + (c2 + c3);
#pragma unroll
            for (int reg = 0; reg < 4; ++reg)
                ctx[(size_t)(b * LQV + q0 + row16 + reg) * DIMV + h * HDV + n0 + r] =
                    f2bf(c[reg] * factor[reg]);
        }

        __syncthreads();   // bar B: all reads of sP(h)/reds(h) done before rewrite
    }

    // ---- attnw final store: full ownership, plain stores ----
    {
        const float inv16 = 1.0f / 16.0f;
        float* ap = attnw + (size_t)(b * LQV + q0 + arow) * LKV + ac0;
#pragma unroll
        for (int j = 0; j < 16; j += 4) {
            float4 o;
            o.x = wacc[j]     * inv16;
            o.y = wacc[j + 1] * inv16;
            o.z = wacc[j + 2] * inv16;
            o.w = wacc[j + 3] * inv16;
            *reinterpret_cast<float4*>(ap + j) = o;
        }
    }
}

// LayerNorm + split-K combine + bias + residual, per row of 1024.
// x = a0 + a1 + out_b + text; then LN(x) -> out (fp32)
__global__ __launch_bounds__(256)
void ln_kernel(const float* __restrict__ a0, const float* __restrict__ a1,
               const float* __restrict__ resid, const float* __restrict__ ob,
               const float* __restrict__ g, const float* __restrict__ bta,
               float* __restrict__ out)
{
    __shared__ float red[8];
    const int row = blockIdx.x;
    const int t = threadIdx.x;
    const int w = t >> 6;
    const float4 v0 = reinterpret_cast<const float4*>(a0 + (size_t)row * DIMV)[t];
    const float4 v1 = reinterpret_cast<const float4*>(a1 + (size_t)row * DIMV)[t];
    const float4 vr = reinterpret_cast<const float4*>(resid + (size_t)row * DIMV)[t];
    const float4 vb = reinterpret_cast<const float4*>(ob)[t];
    float4 xv;
    xv.x = v0.x + v1.x + vr.x + vb.x;
    xv.y = v0.y + v1.y + vr.y + vb.y;
    xv.z = v0.z + v1.z + vr.z + vb.z;
    xv.w = v0.w + v1.w + vr.w + vb.w;

    float s = xv.x + xv.y + xv.z + xv.w;
#pragma unroll
    for (int off = 32; off; off >>= 1) s += __shfl_down(s, off);
    if ((t & 63) == 0) red[w] = s;
    __syncthreads();
    const float mu = (red[0] + red[1] + red[2] + red[3]) * (1.0f / 1024.0f);

    const float d0 = xv.x - mu, d1 = xv.y - mu, d2 = xv.z - mu, d3 = xv.w - mu;
    float s2 = d0 * d0 + d1 * d1 + d2 * d2 + d3 * d3;
#pragma unroll
    for (int off = 32; off; off >>= 1) s2 += __shfl_down(s2, off);
    if ((t & 63) == 0) red[4 + w] = s2;
    __syncthreads();
    const float var = (red[4] + red[5] + red[6] + red[7]) * (1.0f / 1024.0f);
    const float inv = rsqrtf(var + 1e-5f);

    float4 o;
    const int c = t * 4;
    o.x = d0 * inv * g[c + 0] + bta[c + 0];
    o.y = d1 * inv * g[c + 1] + bta[c + 1];
    o.z = d2 * inv * g[c + 2] + bta[c + 2];
    o.w = d3 * inv * g[c + 3] + bta[c + 3];
    reinterpret_cast<float4*>(out + (size_t)row * DIMV)[t] = o;
}

extern "C" void kernel_launch(void* const* d_in, const int* in_sizes, int n_in,
                              void* d_out, int out_size, void* d_ws, size_t ws_size,
                              hipStream_t stream)
{
    const float* text = (const float*)d_in[0];   // (8,512,1024)
    const float* vis  = (const float*)d_in[1];   // (8,1024,1024)
    const float* wqkv = (const float*)d_in[2];   // (3072,1024)
    const float* bqkv = (const float*)d_in[3];   // (3072,)
    const float* outw = (const float*)d_in[4];   // (1024,1024)
    const float* outb = (const float*)d_in[5];   // (1024,)
    const float* lng  = (const float*)d_in[6];   // (1024,)
    const float* lnb  = (const float*)d_in[7];   // (1024,)

    // Workspace overlays (64 MiB). text_bf lives in d_out's out-region
    // (dead until ln_kernel rewrites it). attb0/attb1 overlay kb/vTb
    // (both dead after attn).
    char* ws = (char*)d_ws;
    u16*   vis_bf  = (u16*)(ws);                          // 0-16M
    u16*   ctxb    = (u16*)(ws);                          // 0-8M   (attn w; gemm_out r)
    u16*   wqkv_bf = (u16*)(ws + (size_t)(16u << 20));    // 16-22M
    u16*   outw_bf = (u16*)(ws + (size_t)(22u << 20));    // 22-24M
    u16*   qb      = (u16*)(ws + (size_t)(24u << 20));    // 24-32M
    u16*   kb      = (u16*)(ws + (size_t)(32u << 20));    // 32-48M
    float* attb    = (float*)(ws + (size_t)(32u << 20));  // 32-64M: two 16M split-K bufs
    u16*   vTb     = (u16*)(ws + (size_t)(48u << 20));    // 48-64M

    float* outp  = (float*)d_out;                 // fp32 outputs, concat (out, attn_weights)
    float* attnw = outp + (size_t)4096 * 1024;
    u16*   text_bf = (u16*)outp;                  // 8MB scratch in out-region

    const dim3 blk(256);
    // stage 0: all casts, one dispatch
    cast_all<<<dim3(16384), blk, 0, stream>>>(vis, wqkv, outw, text,
                                              vis_bf, wqkv_bf, outw_bf, text_bf);
    // stage 1: Q,K,V^T projections, one dispatch (1280 blocks)
    qkv_gemm<<<dim3(160, 8), blk, 0, stream>>>(text_bf, vis_bf, wqkv_bf, bqkv, qb, kb, vTb);
    // stage 2: attention; 1024-thr blocks (16 waves/CU), 4 groups x 4 heads
    attn_kernel<<<dim3(8, 32), dim3(1024), 0, stream>>>(qb, kb, vTb, ctxb, attnw);
    // stage 3: split-K output GEMM -> raw partials (512 blocks, 2/CU)
    gemm_out<<<dim3(32, 8, 2), blk, 0, stream>>>(ctxb, outw_bf, attb);
    // stage 4: combine + bias + residual + layernorm -> out (fp32)
    ln_kernel<<<dim3(4096), blk, 0, stream>>>(attb, attb + (size_t)4096 * 1024,
                                              text, outb, lng, lnb, outp);
}